// Round 3
// baseline (4217.538 us; speedup 1.0000x reference)
//
#include <hip/hip_runtime.h>

constexpr int T  = 1024;
constexpr int B  = 32;
constexpr int I  = 64;
constexpr int H  = 1024;
constexpr int OF = 64;
constexpr int OC = 8;
constexpr int K  = H + I;     // 1088 = h2h ++ i2h folded
constexpr int NGROUPS = 16;   // sync groups (2 batches each)
constexpr int NMEMB   = 16;   // workgroups per group
constexpr int BPG = 2;        // batches per group
constexpr int CH  = 136;      // per-lane contiguous k-chunk (K/8)
constexpr int CHP = 140;      // padded chunk stride: 12*l8 mod 32 covers all 8 quad groups
constexpr int BSTR = 8 * CHP; // 1120 words per batch in LDS
constexpr long long OUT1_OFF = (long long)T * B * OF;
constexpr long long OUT2_OFF = (long long)T * B * (OF + OC);

// Agent-scope relaxed (coherent, fence-free) ops: emit global_{load,store} sc0 sc1
// (bypass L1/L2, meet at the device coherence point). No buffer_wbl2/buffer_inv.
__device__ __forceinline__ void st_agent_f32(float* p, float v) {
  __hip_atomic_store(p, v, __ATOMIC_RELAXED, __HIP_MEMORY_SCOPE_AGENT);
}
__device__ __forceinline__ unsigned long long ld_agent_u64(const float* p) {
  return __hip_atomic_load((const unsigned long long*)p, __ATOMIC_RELAXED,
                           __HIP_MEMORY_SCOPE_AGENT);
}
__device__ __forceinline__ bool has_sent(unsigned long long v) {
  return ((unsigned)v == 0xFFFFFFFFu) || ((unsigned)(v >> 32) == 0xFFFFFFFFu);
}

// ---------------------------------------------------------------------------
// Recurrence: 256 persistent WGs x 512 threads (1/CU), group g = bid&15 owns
// batches {2g, 2g+1}; member m = bid>>4 owns rows [m*64, m*64+64).
// Thread (jrel = tid>>3, l8 = tid&7): row j0+jrel, contiguous k-chunk
// [l8*136, l8*136+136). Weights register-stationary (34 float4/thread).
// Exchange: sentinel-polled coherent loads on rate_all (NaN 0xFFFFFFFF fill
// per call) — no counters, no fences, one barrier per step (double-buffered
// LDS state).
// ---------------------------------------------------------------------------
__global__ __launch_bounds__(512, 2) void rnn_recur(
    const float* __restrict__ input_sig, const float* __restrict__ rate0,
    const float* __restrict__ i2h_w, const float* __restrict__ i2h_b,
    const float* __restrict__ h2h_w, const float* __restrict__ h2h_b,
    float* __restrict__ rate_all)
{
  const int tid = threadIdx.x;
  const int bid = blockIdx.x;
  const int g   = bid & (NGROUPS - 1);
  const int m   = bid >> 4;
  const int j0  = m * 64;
  const int l8  = tid & 7;
  const int jrel = tid >> 3;
  const int j   = j0 + jrel;
  const int bG  = g * BPG;

  __shared__ float r_lds[2][BPG * BSTR];  // double-buffered state, padded layout

  // ---- register-stationary weights: 34 float4 = 136 fp32 per thread
  float4 w4[34];
#pragma unroll
  for (int q = 0; q < 34; ++q) {
    const int k = l8 * CH + q * 4;
    w4[q] = (k < H) ? *(const float4*)(h2h_w + (long long)j * H + k)
                    : *(const float4*)(i2h_w + (long long)j * I + (k - H));
  }
  const float bsum = h2h_b[j] + i2h_b[j];
  const int posj = (j / CH) * CHP + (j % CH);  // padded LDS position of r[j]

  // ---- initial stage into buf0: rate0 (plain cached) + input_sig[0]
  {
    const int b = tid >> 8, u4 = tid & 255;
    const int k0 = u4 * 4, c = k0 / CH, off = k0 - c * CH;  // quads never straddle (136%4==0)
    float4 v = *(const float4*)(rate0 + (long long)(bG + b) * H + k0);
    *(float4*)&r_lds[0][b * BSTR + c * CHP + off] = v;
    if (tid < 32) {
      const int b2 = tid >> 4, iq = tid & 15;
      float4 u = *(const float4*)(input_sig + (long long)(bG + b2) * I + iq * 4);
      *(float4*)&r_lds[0][b2 * BSTR + 7 * CHP + 72 + iq * 4] = u;  // k in [1024,1088)
    }
  }
  __syncthreads();

  for (int t = 0; t < T; ++t) {
    const int cur = t & 1, nxt = cur ^ 1;
    const float* Rb = &r_lds[cur][0];

    float a0 = 0.f, a1 = 0.f;
#pragma unroll
    for (int q = 0; q < 34; ++q) {
      const float4 r0 = *(const float4*)&Rb[l8 * CHP + q * 4];
      const float4 r1 = *(const float4*)&Rb[BSTR + l8 * CHP + q * 4];
      a0 = fmaf(w4[q].x, r0.x, a0); a1 = fmaf(w4[q].x, r1.x, a1);
      a0 = fmaf(w4[q].y, r0.y, a0); a1 = fmaf(w4[q].y, r1.y, a1);
      a0 = fmaf(w4[q].z, r0.z, a0); a1 = fmaf(w4[q].z, r1.z, a1);
      a0 = fmaf(w4[q].w, r0.w, a0); a1 = fmaf(w4[q].w, r1.w, a1);
    }
    // reduce across the 8 k-slice lanes (3 rounds, stays inside each 8-group)
#pragma unroll
    for (int off = 4; off >= 1; off >>= 1) {
      a0 += __shfl_xor(a0, off, 64);
      a1 += __shfl_xor(a1, off, 64);
    }
    // lanes l8=0/1 own batch 0/1 of row j: bias + tanh + leaky update + store
    if (l8 < 2) {
      const float pre  = ((l8 == 0) ? a0 : a1) + bsum;
      const float rold = r_lds[cur][l8 * BSTR + posj];
      const float rnew = 0.9f * rold + 0.1f * tanhf(pre);
      st_agent_f32(&rate_all[((long long)t * B + (bG + l8)) * H + j], rnew);
    }

    if (t + 1 < T) {
      // stage input_sig[t+1] (plain cached, in flight during the poll)
      if (tid < 32) {
        const int b2 = tid >> 4, iq = tid & 15;
        float4 u = *(const float4*)(input_sig +
            ((long long)(t + 1) * B + bG + b2) * I + iq * 4);
        *(float4*)&r_lds[nxt][b2 * BSTR + 7 * CHP + 72 + iq * 4] = u;
      }
      // sentinel-polled restage of r_t: 2 batches x 512 u64 per WG
      const float* srcR = rate_all + ((long long)t * B + bG) * H;
      const float* p0 = srcR + 2 * tid;       // batch 0, k = 2*tid
      const float* p1 = srcR + H + 2 * tid;   // batch 1
      unsigned long long v0 = ld_agent_u64(p0);
      unsigned long long v1 = ld_agent_u64(p1);
      const int c = tid / 68, off = 2 * tid - c * CH;
      while (has_sent(v0)) v0 = ld_agent_u64(p0);
      *(unsigned long long*)&r_lds[nxt][c * CHP + off] = v0;
      while (has_sent(v1)) v1 = ld_agent_u64(p1);
      *(unsigned long long*)&r_lds[nxt][BSTR + c * CHP + off] = v1;
    }
    __syncthreads();
  }
}

// ---------------------------------------------------------------------------
// Readout: C[32768,72] = rate_all[32768,1024] x [h2o_w;h2o_ctx_w]^T + bias
// ---------------------------------------------------------------------------
__global__ __launch_bounds__(256) void rnn_readout(
    const float* __restrict__ rate_all,
    const float* __restrict__ h2o_w, const float* __restrict__ h2o_b,
    const float* __restrict__ h2o_ctx_w, const float* __restrict__ h2o_ctx_b,
    float* __restrict__ out0, float* __restrict__ out1)
{
  constexpr int RB = 128;
  constexpr int HC = 128;
  constexpr int SR = HC + 1;
  __shared__ float rl[RB * SR];
  __shared__ float wl[72 * SR];

  const int tid = threadIdx.x;
  const long long row0 = (long long)blockIdx.x * RB;
  const int rb = tid & 31, og = tid >> 5;

  float acc[4][9];
#pragma unroll
  for (int c = 0; c < 4; ++c)
#pragma unroll
    for (int i = 0; i < 9; ++i) acc[c][i] = 0.f;

  for (int hc = 0; hc < H / HC; ++hc) {
#pragma unroll
    for (int i = 0; i < 16; ++i) {
      const int q = i * 256 + tid;
      const int row = q >> 5, hq = q & 31;
      float4 v = *(const float4*)(rate_all + (row0 + row) * H + hc * HC + hq * 4);
      float* d = &rl[row * SR + hq * 4];
      d[0] = v.x; d[1] = v.y; d[2] = v.z; d[3] = v.w;
    }
#pragma unroll
    for (int i = 0; i < 9; ++i) {
      const int q = i * 256 + tid;
      const int o = q >> 5, hq = q & 31;
      const float* src = (o < OF) ? (h2o_w + (long long)o * H)
                                  : (h2o_ctx_w + (long long)(o - OF) * H);
      float4 v = *(const float4*)(src + hc * HC + hq * 4);
      float* d = &wl[o * SR + hq * 4];
      d[0] = v.x; d[1] = v.y; d[2] = v.z; d[3] = v.w;
    }
    __syncthreads();

#pragma unroll 4
    for (int h = 0; h < HC; ++h) {
      const float r0 = rl[(rb)      * SR + h];
      const float r1 = rl[(rb + 32) * SR + h];
      const float r2 = rl[(rb + 64) * SR + h];
      const float r3 = rl[(rb + 96) * SR + h];
#pragma unroll
      for (int i = 0; i < 9; ++i) {
        const float wv = wl[(og * 9 + i) * SR + h];
        acc[0][i] = fmaf(r0, wv, acc[0][i]);
        acc[1][i] = fmaf(r1, wv, acc[1][i]);
        acc[2][i] = fmaf(r2, wv, acc[2][i]);
        acc[3][i] = fmaf(r3, wv, acc[3][i]);
      }
    }
    __syncthreads();
  }

#pragma unroll
  for (int c = 0; c < 4; ++c) {
    const long long row = row0 + rb + 32 * c;
#pragma unroll
    for (int i = 0; i < 9; ++i) {
      const int o = og * 9 + i;
      if (o < OF) out0[row * OF + o] = acc[c][i] + h2o_b[o];
      else        out1[row * OC + (o - OF)] = acc[c][i] + h2o_ctx_b[o - OF];
    }
  }
}

extern "C" void kernel_launch(void* const* d_in, const int* in_sizes, int n_in,
                              void* d_out, int out_size, void* d_ws, size_t ws_size,
                              hipStream_t stream) {
  (void)in_sizes; (void)n_in; (void)d_ws; (void)ws_size; (void)out_size;
  const float* input_sig = (const float*)d_in[0];
  const float* rate0     = (const float*)d_in[1];
  const float* i2h_w     = (const float*)d_in[2];
  const float* i2h_b     = (const float*)d_in[3];
  const float* h2h_w     = (const float*)d_in[4];
  const float* h2h_b     = (const float*)d_in[5];
  const float* h2o_w     = (const float*)d_in[6];
  const float* h2o_b     = (const float*)d_in[7];
  const float* h2o_ctx_w = (const float*)d_in[8];
  const float* h2o_ctx_b = (const float*)d_in[9];

  float* out      = (float*)d_out;
  float* out0     = out;
  float* out1     = out + OUT1_OFF;
  float* rate_all = out + OUT2_OFF;

  // Sentinel-fill rate_all with NaN pattern 0xFFFFFFFF each call; finite
  // arithmetic can never reproduce it, so a non-sentinel read == data ready.
  hipMemsetAsync(rate_all, 0xFF, (size_t)T * B * H * sizeof(float), stream);
  hipLaunchKernelGGL(rnn_recur, dim3(NGROUPS * NMEMB), dim3(512), 0, stream,
                     input_sig, rate0, i2h_w, i2h_b, h2h_w, h2h_b, rate_all);
  hipLaunchKernelGGL(rnn_readout, dim3(256), dim3(256), 0, stream,
                     rate_all, h2o_w, h2o_b, h2o_ctx_w, h2o_ctx_b, out0, out1);
}